// Round 1
// baseline (2358.697 us; speedup 1.0000x reference)
//
#include <hip/hip_runtime.h>
#include <hip/hip_bf16.h>
#include <math.h>

#define NPIX    16384
#define OBSD    768
#define OBJ     128
#define NS      32
#define HIDD    256
#define RELD    64
#define ACTD    16
#define QSCALE  0.08838834764831845f   /* 128^-0.5 */
#define LNEPS   1e-5f
#define ATEPS   1e-8f
#define DTC     0.1f

/* ---- workspace layout (floats) ---- */
#define OFF_STATS 0                         /* 16384*2          */
#define OFF_KV    (OFF_STATS + NPIX*2)      /* 16384*256        */
#define OFF_SLOTS (OFF_KV + NPIX*256)       /* 4096             */
#define OFF_Q     (OFF_SLOTS + 4096)        /* 4096             */
#define OFF_H     (OFF_Q + 4096)            /* 4096 (unused now)*/
#define OFF_APART (OFF_H + 4096)            /* 256*4128         */
#define OFF_OBJ   (OFF_APART + 256*4128)    /* 4096             */
#define OFF_FEAT  (OFF_OBJ + 4096)          /* 4096 + 65536     */
#define OFF_P1    (OFF_FEAT + 69632)        /* 1024*1536        */
#define OFF_HREND (OFF_P1 + 1024*1536)      /* 1536             */
#define OFF_P3    (OFF_HREND + 1536)        /* 48*768           */
#define OFF_P2    (OFF_P3 + 48*768)         /* 16*1536          */

/* ================= LN stats: mean/rstd per pixel row ================= */
__global__ __launch_bounds__(256) void k_stats(const float* __restrict__ obs,
                                               float* __restrict__ stats)
{
    int lane = threadIdx.x & 63;
    int w    = threadIdx.x >> 6;
    int row  = blockIdx.x * 4 + w;
    const float* o = obs + (size_t)row * OBSD;
    float s = 0.f, s2 = 0.f;
    #pragma unroll
    for (int i = 0; i < 12; ++i) { float v = o[lane + 64*i]; s += v; s2 += v*v; }
    #pragma unroll
    for (int off = 32; off > 0; off >>= 1) {
        s  += __shfl_down(s,  off);
        s2 += __shfl_down(s2, off);
    }
    if (lane == 0) {
        float m   = s  * (1.f/OBSD);
        float var = s2 * (1.f/OBSD) - m*m;
        stats[row*2]   = m;
        stats[row*2+1] = rsqrtf(var + LNEPS);
    }
}

/* ====== kv GEMM: x_ln(16384x768) @ [Wk|Wv](768x256) -> kv[n][256] ======
   Register-double-buffered: global loads for tile k+1 issue before the
   FMA block for tile k (latency hidden; 1 barrier per K-step).
   KVA=132 keeps float4 alignment for A-fragment ds_read_b128.          */
#define KVA 132
__global__ __launch_bounds__(256, 1) void k_kv(
    const float* __restrict__ obs, const float* __restrict__ stats,
    const float* __restrict__ g, const float* __restrict__ b,
    const float* __restrict__ Wk, const float* __restrict__ Wv,
    float* __restrict__ kv)
{
    __shared__ float As[2][32*KVA];   /* [kk][m] */
    __shared__ float Bs[2][32*128];   /* [kk][jj] */
    int t    = threadIdx.x;
    int m0   = blockIdx.x * 128;
    int nsel = blockIdx.y;
    const float* W = nsel ? Wv : Wk;
    int tx = t & 15, ty = t >> 4;          /* compute mapping  */
    int ka = t & 31, ma = t >> 5;          /* A staging: col ka, rows ma+8r */
    int jb = t & 127, kb = t >> 7;         /* B staging: col jb, rows kb+2r */

    float acc[8][8];
    #pragma unroll
    for (int i = 0; i < 8; ++i) {
        #pragma unroll
        for (int j = 0; j < 8; ++j) acc[i][j] = 0.f;
    }

    /* per-thread row stats held in registers for the whole kernel */
    float smr[16], srr[16];
    #pragma unroll
    for (int r = 0; r < 16; ++r) {
        smr[r] = stats[(size_t)(m0 + ma + 8*r)*2];
        srr[r] = stats[(size_t)(m0 + ma + 8*r)*2 + 1];
    }

    float pa[16], pb[16], gv, cv;
    /* prefetch + store tile 0 */
    #pragma unroll
    for (int r = 0; r < 16; ++r) pa[r] = obs[(size_t)(m0 + ma + 8*r)*OBSD + ka];
    #pragma unroll
    for (int r = 0; r < 16; ++r) pb[r] = W[(size_t)(kb + 2*r)*128 + jb];
    gv = g[ka]; cv = b[ka];
    #pragma unroll
    for (int r = 0; r < 16; ++r)
        As[0][ka*KVA + ma + 8*r] = (pa[r] - smr[r]) * srr[r] * gv + cv;
    #pragma unroll
    for (int r = 0; r < 16; ++r)
        Bs[0][(kb + 2*r)*128 + jb] = pb[r];
    __syncthreads();

    for (int ks = 0; ks < 24; ++ks) {
        int cur = ks & 1;
        if (ks < 23) {                       /* issue next-tile loads */
            int k0 = (ks + 1) * 32;
            #pragma unroll
            for (int r = 0; r < 16; ++r)
                pa[r] = obs[(size_t)(m0 + ma + 8*r)*OBSD + k0 + ka];
            #pragma unroll
            for (int r = 0; r < 16; ++r)
                pb[r] = W[(size_t)(k0 + kb + 2*r)*128 + jb];
            gv = g[k0 + ka]; cv = b[k0 + ka];
        }
        #pragma unroll
        for (int kk = 0; kk < 32; ++kk) {    /* compute current tile */
            float4 a0 = *(const float4*)&As[cur][kk*KVA + ty*8];
            float4 a1 = *(const float4*)&As[cur][kk*KVA + ty*8 + 4];
            float4 u0 = *(const float4*)&Bs[cur][kk*128 + tx*8];
            float4 u1 = *(const float4*)&Bs[cur][kk*128 + tx*8 + 4];
            float a8[8] = {a0.x,a0.y,a0.z,a0.w,a1.x,a1.y,a1.z,a1.w};
            float b8[8] = {u0.x,u0.y,u0.z,u0.w,u1.x,u1.y,u1.z,u1.w};
            #pragma unroll
            for (int i = 0; i < 8; ++i) {
                #pragma unroll
                for (int j = 0; j < 8; ++j)
                    acc[i][j] = fmaf(a8[i], b8[j], acc[i][j]);
            }
        }
        if (ks < 23) {                       /* store into other buffer */
            int nb = cur ^ 1;
            #pragma unroll
            for (int r = 0; r < 16; ++r)
                As[nb][ka*KVA + ma + 8*r] = (pa[r] - smr[r]) * srr[r] * gv + cv;
            #pragma unroll
            for (int r = 0; r < 16; ++r)
                Bs[nb][(kb + 2*r)*128 + jb] = pb[r];
        }
        __syncthreads();
    }

    #pragma unroll
    for (int i = 0; i < 8; ++i) {
        size_t row = (size_t)(m0 + ty*8 + i);
        float4 o0 = make_float4(acc[i][0], acc[i][1], acc[i][2], acc[i][3]);
        float4 o1 = make_float4(acc[i][4], acc[i][5], acc[i][6], acc[i][7]);
        *(float4*)&kv[row*256 + nsel*128 + tx*8]     = o0;
        *(float4*)&kv[row*256 + nsel*128 + tx*8 + 4] = o1;
    }
}

/* ================= slot init ================= */
__global__ __launch_bounds__(256) void k_slots_init(
    const float* __restrict__ mu, const float* __restrict__ lsig,
    const float* __restrict__ noise, float* __restrict__ slots)
{
    int id = blockIdx.x * 256 + threadIdx.x;
    int d  = id & 127;
    slots[id] = mu[d] + expf(lsig[d]) * noise[id];
}

/* ================= q = LN(slots) @ Wq (first iteration only) ================= */
__global__ __launch_bounds__(128) void k_q(
    const float* __restrict__ slots, const float* __restrict__ Wq,
    const float* __restrict__ g, const float* __restrict__ b,
    float* __restrict__ qg)
{
    int s = blockIdx.x, t = threadIdx.x;
    float x = slots[s*128 + t];
    __shared__ float red[128];
    __shared__ float hh[128];
    red[t] = x; __syncthreads();
    for (int off = 64; off > 0; off >>= 1) { if (t < off) red[t] += red[t+off]; __syncthreads(); }
    float mean = red[0] * (1.f/128.f); __syncthreads();
    float dx = x - mean;
    red[t] = dx*dx; __syncthreads();
    for (int off = 64; off > 0; off >>= 1) { if (t < off) red[t] += red[t+off]; __syncthreads(); }
    float var = red[0] * (1.f/128.f);
    hh[t] = dx * rsqrtf(var + LNEPS) * g[t] + b[t];
    __syncthreads();
    float acc = 0.f;
    for (int d = 0; d < 128; ++d) acc = fmaf(hh[d], Wq[d*128 + t], acc);
    qg[s*128 + t] = acc;
}

/* ====== attention tile: 64 pixels/block; softmax over slots; partial U,Ssum ====== */
#define STK 129
#define STQ 132
#define STT 36
__global__ __launch_bounds__(256) void k_attn(
    const float* __restrict__ kv, const float* __restrict__ qg,
    float* __restrict__ part)
{
    __shared__ float q_lds[NS*STQ];
    __shared__ float k_lds[64*STK];
    __shared__ float at[64*STT];
    int t   = threadIdx.x;
    int px0 = blockIdx.x * 64;
    #pragma unroll
    for (int r = 0; r < 16; ++r) {
        int id = t + 256*r;
        int s = id >> 7, d = id & 127;
        q_lds[s*STQ + d] = qg[id];
    }
    #pragma unroll
    for (int r = 0; r < 32; ++r) {
        int id = t + 256*r;
        int p = id >> 7, d = id & 127;
        k_lds[p*STK + d] = kv[(size_t)(px0+p)*256 + d];
    }
    __syncthreads();

    /* logits: wave w handles slot set {4u+w}, lane = pixel */
    int wv = t >> 6, p = t & 63;
    float acc[8];
    #pragma unroll
    for (int u = 0; u < 8; ++u) acc[u] = 0.f;
    for (int dc = 0; dc < 4; ++dc) {
        float kr[32];
        #pragma unroll
        for (int d = 0; d < 32; ++d) kr[d] = k_lds[p*STK + dc*32 + d];
        #pragma unroll
        for (int u = 0; u < 8; ++u) {
            int s = u*4 + wv;
            const float* qp = &q_lds[s*STQ + dc*32];
            #pragma unroll
            for (int ii = 0; ii < 8; ++ii) {
                float4 q4 = *(const float4*)(qp + 4*ii);
                acc[u] = fmaf(q4.x, kr[4*ii+0], acc[u]);
                acc[u] = fmaf(q4.y, kr[4*ii+1], acc[u]);
                acc[u] = fmaf(q4.z, kr[4*ii+2], acc[u]);
                acc[u] = fmaf(q4.w, kr[4*ii+3], acc[u]);
            }
        }
    }
    #pragma unroll
    for (int u = 0; u < 8; ++u) at[p*STT + u*4 + wv] = acc[u] * QSCALE;
    __syncthreads();

    /* softmax over slots, per pixel */
    if (t < 64) {
        float mx = -1e30f;
        #pragma unroll
        for (int s = 0; s < NS; ++s) mx = fmaxf(mx, at[t*STT + s]);
        float smv = 0.f;
        #pragma unroll
        for (int s = 0; s < NS; ++s) { float e = expf(at[t*STT + s] - mx); at[t*STT + s] = e; smv += e; }
        float inv = 1.f / smv;
        #pragma unroll
        for (int s = 0; s < NS; ++s) at[t*STT + s] *= inv;
    }
    __syncthreads();

    /* U[s][d] partial + Ssum[s] partial */
    int d = t & 127, sh = t >> 7;
    float u16[16];
    #pragma unroll
    for (int i = 0; i < 16; ++i) u16[i] = 0.f;
    const float* vbase = kv + (size_t)px0*256 + 128 + d;
    #pragma unroll 4
    for (int pp = 0; pp < 64; ++pp) {
        float vv = vbase[(size_t)pp*256];
        const float4* ap = (const float4*)&at[pp*STT + sh*16];
        #pragma unroll
        for (int gg = 0; gg < 4; ++gg) {
            float4 a4 = ap[gg];
            u16[4*gg+0] = fmaf(a4.x, vv, u16[4*gg+0]);
            u16[4*gg+1] = fmaf(a4.y, vv, u16[4*gg+1]);
            u16[4*gg+2] = fmaf(a4.z, vv, u16[4*gg+2]);
            u16[4*gg+3] = fmaf(a4.w, vv, u16[4*gg+3]);
        }
    }
    float* P = part + (size_t)blockIdx.x * 4128;
    #pragma unroll
    for (int g2 = 0; g2 < 16; ++g2) P[(sh*16 + g2)*128 + d] = u16[g2];
    if (t < 32) {
        float ss = 0.f;
        for (int pp = 0; pp < 64; ++pp) ss += at[pp*STT + t];
        P[4096 + t] = ss;
    }
}

/* ====== fused: reduce partials -> slot update -> LN -> MLP residual -> q(next) ====== */
__global__ __launch_bounds__(256) void k_umq(
    const float* __restrict__ part, float* __restrict__ slots,
    const float* __restrict__ gm, const float* __restrict__ bm,
    const float* __restrict__ w1, const float* __restrict__ b1,
    const float* __restrict__ w2, const float* __restrict__ b2,
    const float* __restrict__ gs, const float* __restrict__ bs,
    const float* __restrict__ Wq, float* __restrict__ qg, int do_q)
{
    int s = blockIdx.x, t = threadIdx.x;
    int d = t & 127, half = t >> 7;
    __shared__ float red[256];
    __shared__ float ssred[2];
    __shared__ float xs[128], hm[128], hid[256];

    /* partial reduce: halves split the 256 attn blocks */
    float u = 0.f, ss = 0.f;
    const float* P0 = part + (size_t)(half * 128) * 4128;
    for (int bb = 0; bb < 128; ++bb) {
        const float* P = P0 + (size_t)bb * 4128;
        u  += P[s*128 + d];
        ss += P[4096 + s];
    }
    red[t] = u;
    if (d == 0) ssred[half] = ss;
    __syncthreads();
    if (half == 0)
        xs[d] = slots[s*128 + d] + (red[d] + red[d+128]) / (ssred[0] + ssred[1] + ATEPS);
    __syncthreads();

    /* LN(xs) -> hm */
    red[t] = (half == 0) ? xs[d] : 0.f;
    __syncthreads();
    #pragma unroll
    for (int off = 128; off > 0; off >>= 1) { if (t < off) red[t] += red[t+off]; __syncthreads(); }
    float mean = red[0] * (1.f/128.f);
    __syncthreads();
    { float dx = (half == 0) ? (xs[d] - mean) : 0.f; red[t] = dx*dx; }
    __syncthreads();
    #pragma unroll
    for (int off = 128; off > 0; off >>= 1) { if (t < off) red[t] += red[t+off]; __syncthreads(); }
    float rstd = rsqrtf(red[0] * (1.f/128.f) + LNEPS);
    __syncthreads();
    if (half == 0) hm[d] = (xs[d] - mean) * rstd * gm[d] + bm[d];
    __syncthreads();

    /* mlp: hid = relu(hm@w1+b1); slots = xs + hid@w2+b2 */
    float a = b1[t];
    for (int c = 0; c < 128; ++c) a = fmaf(hm[c], w1[c*256 + t], a);
    hid[t] = fmaxf(a, 0.f);
    __syncthreads();
    if (half == 0) {
        float o = b2[d];
        for (int j = 0; j < 256; ++j) o = fmaf(hid[j], w2[j*128 + d], o);
        float xn = xs[d] + o;
        slots[s*128 + d] = xn;
        xs[d] = xn;
    }
    __syncthreads();

    if (do_q) {
        /* q for next iteration: LN(slots_new) @ Wq */
        red[t] = (half == 0) ? xs[d] : 0.f;
        __syncthreads();
        #pragma unroll
        for (int off = 128; off > 0; off >>= 1) { if (t < off) red[t] += red[t+off]; __syncthreads(); }
        float m2 = red[0] * (1.f/128.f);
        __syncthreads();
        { float dx = (half == 0) ? (xs[d] - m2) : 0.f; red[t] = dx*dx; }
        __syncthreads();
        #pragma unroll
        for (int off = 128; off > 0; off >>= 1) { if (t < off) red[t] += red[t+off]; __syncthreads(); }
        float r2 = rsqrtf(red[0] * (1.f/128.f) + LNEPS);
        __syncthreads();
        if (half == 0) hm[d] = (xs[d] - m2) * r2 * gs[d] + bs[d];
        __syncthreads();
        float acc = 0.f;
        for (int c = half*64; c < half*64 + 64; ++c) acc = fmaf(hm[c], Wq[c*128 + d], acc);
        red[t] = acc;
        __syncthreads();
        if (half == 0) qg[s*128 + d] = red[d] + red[d+128];
    }
}

/* ====== fused: objects = prop MLP; then dynamics -> feat[0:4096] ====== */
__global__ __launch_bounds__(256) void k_propdyn(
    const float* __restrict__ slots,
    const float* __restrict__ pw1, const float* __restrict__ pb1,
    const float* __restrict__ pw2, const float* __restrict__ pb2,
    const float* __restrict__ action,
    const float* __restrict__ dw1, const float* __restrict__ db1,
    const float* __restrict__ dw2, const float* __restrict__ db2,
    const float* __restrict__ dw3, const float* __restrict__ db3,
    const float* __restrict__ gravity,
    float* __restrict__ objects, float* __restrict__ feat)
{
    int s = blockIdx.x, t = threadIdx.x;
    __shared__ float h[128], hid[256], inp[144], h2[256];
    if (t < 128) h[t] = slots[s*128 + t];
    __syncthreads();
    float a = pb1[t];
    for (int c = 0; c < 128; ++c) a = fmaf(h[c], pw1[c*256 + t], a);
    hid[t] = fmaxf(a, 0.f);
    __syncthreads();
    if (t < 128) {
        float o = pb2[t];
        for (int j = 0; j < 256; ++j) o = fmaf(hid[j], pw2[j*128 + t], o);
        objects[s*128 + t] = o;
        inp[t] = o;
    } else if (t < 144) {
        inp[t] = action[t - 128];
    }
    __syncthreads();            /* all hid reads done; inp visible */
    float a1 = db1[t];
    for (int c = 0; c < 144; ++c) a1 = fmaf(inp[c], dw1[c*256 + t], a1);
    hid[t] = fmaxf(a1, 0.f);    /* safe: hid readers all before last sync */
    __syncthreads();
    float a2 = db2[t];
    for (int c = 0; c < 256; ++c) a2 = fmaf(hid[c], dw2[c*256 + t], a2);
    h2[t] = fmaxf(a2, 0.f);
    __syncthreads();
    if (t < 128) {
        float dlt = db3[t];
        for (int c = 0; c < 256; ++c) dlt = fmaf(h2[c], dw3[c*128 + t], dlt);
        if (t < 3) dlt += gravity[t] * DTC;
        feat[s*128 + t] = inp[t] + dlt * DTC;
    }
}

/* ====== relations: per (i,j) pair MLP 256->128(relu)->64 ====== */
__global__ __launch_bounds__(128) void k_rel(
    const float* __restrict__ objects, const float* __restrict__ w1, const float* __restrict__ b1,
    const float* __restrict__ w2, const float* __restrict__ b2, float* __restrict__ rel_out)
{
    int pr = blockIdx.x; int i = pr >> 5, j = pr & 31; int t = threadIdx.x;
    __shared__ float pair[256], hid[128];
    pair[t]       = objects[i*128 + t];
    pair[128 + t] = objects[j*128 + t];
    __syncthreads();
    float a = b1[t];
    for (int c = 0; c < 256; ++c) a = fmaf(pair[c], w1[c*128 + t], a);
    hid[t] = fmaxf(a, 0.f);
    __syncthreads();
    if (t < 64) {
        float o = b2[t];
        for (int c = 0; c < 128; ++c) o = fmaf(hid[c], w2[c*64 + t], o);
        rel_out[(size_t)pr*64 + t] = o;
    }
}

/* ====== renderer stage 1: feat @ rend_w1 partials (the 428 MB read) ====== */
__global__ __launch_bounds__(384) void k_rend1(
    const float* __restrict__ feat, const float* __restrict__ w1, float* __restrict__ p1)
{
    int b = blockIdx.x, t = threadIdx.x;
    float4 acc = make_float4(0.f, 0.f, 0.f, 0.f);
    int i0 = b * 68;
    #pragma unroll 4
    for (int r = 0; r < 68; ++r) {
        int i = i0 + r;
        float f = feat[i];
        float4 w = *(const float4*)(w1 + (size_t)i * 1536 + 4*t);
        acc.x = fmaf(f, w.x, acc.x);
        acc.y = fmaf(f, w.y, acc.y);
        acc.z = fmaf(f, w.z, acc.z);
        acc.w = fmaf(f, w.w, acc.w);
    }
    *(float4*)(p1 + (size_t)b * 1536 + 4*t) = acc;
}

/* ====== renderer stage 2a: tree-reduce partials (96 blocks) ====== */
__global__ __launch_bounds__(256) void k_rend2a(
    const float* __restrict__ p1, float* __restrict__ p2)
{
    int j  = blockIdx.x * 256 + threadIdx.x;
    int sl = blockIdx.y;
    const float* P = p1 + (size_t)sl * 64 * 1536;
    float a0 = 0.f, a1 = 0.f, a2 = 0.f, a3 = 0.f;
    #pragma unroll 4
    for (int bb = 0; bb < 64; bb += 4) {
        a0 += P[(size_t)(bb+0)*1536 + j];
        a1 += P[(size_t)(bb+1)*1536 + j];
        a2 += P[(size_t)(bb+2)*1536 + j];
        a3 += P[(size_t)(bb+3)*1536 + j];
    }
    p2[sl*1536 + j] = (a0+a1) + (a2+a3);
}

/* ====== renderer stage 2b: finish + bias + relu -> h(1536) ====== */
__global__ __launch_bounds__(256) void k_rend2b(
    const float* __restrict__ p2, const float* __restrict__ b1, float* __restrict__ h)
{
    int j = blockIdx.x * 256 + threadIdx.x;
    float a = b1[j];
    #pragma unroll
    for (int sl = 0; sl < 16; ++sl) a += p2[sl*1536 + j];
    h[j] = fmaxf(a, 0.f);
}

/* ====== renderer stage 3: h @ rend_w2 partials ====== */
__global__ __launch_bounds__(256) void k_rend3(
    const float* __restrict__ h, const float* __restrict__ w2, float* __restrict__ p3)
{
    int bj = blockIdx.x, t = threadIdx.x;
    int j0 = bj * 32;
    float a0 = 0.f, a1 = 0.f, a2 = 0.f;
    #pragma unroll
    for (int j = 0; j < 32; ++j) {
        float hj = h[j0 + j];
        const float* w = w2 + (size_t)(j0 + j) * 768;
        a0 = fmaf(hj, w[t],       a0);
        a1 = fmaf(hj, w[t + 256], a1);
        a2 = fmaf(hj, w[t + 512], a2);
    }
    p3[(size_t)bj*768 + t]       = a0;
    p3[(size_t)bj*768 + t + 256] = a1;
    p3[(size_t)bj*768 + t + 512] = a2;
}

/* ====== renderer stage 4: reduce + bias -> out(768) ====== */
__global__ __launch_bounds__(256) void k_rend4(
    const float* __restrict__ p3, const float* __restrict__ b2, float* __restrict__ out)
{
    int m = blockIdx.x * 256 + threadIdx.x;
    float a = b2[m];
    #pragma unroll
    for (int bj = 0; bj < 48; ++bj) a += p3[(size_t)bj*768 + m];
    out[m] = a;
}

extern "C" void kernel_launch(void* const* d_in, const int* in_sizes, int n_in,
                              void* d_out, int out_size, void* d_ws, size_t ws_size,
                              hipStream_t stream) {
    (void)in_sizes; (void)n_in; (void)out_size; (void)ws_size;
    const float* obs      = (const float*)d_in[0];
    const float* action   = (const float*)d_in[1];
    const float* noise    = (const float*)d_in[2];
    const float* mu       = (const float*)d_in[3];
    const float* lsig     = (const float*)d_in[4];
    const float* ln_in_g  = (const float*)d_in[5];
    const float* ln_in_b  = (const float*)d_in[6];
    const float* ln_s_g   = (const float*)d_in[7];
    const float* ln_s_b   = (const float*)d_in[8];
    const float* ln_m_g   = (const float*)d_in[9];
    const float* ln_m_b   = (const float*)d_in[10];
    const float* Wq       = (const float*)d_in[11];
    const float* Wk       = (const float*)d_in[12];
    const float* Wv       = (const float*)d_in[13];
    const float* mlp_w1   = (const float*)d_in[14];
    const float* mlp_b1   = (const float*)d_in[15];
    const float* mlp_w2   = (const float*)d_in[16];
    const float* mlp_b2   = (const float*)d_in[17];
    const float* prop_w1  = (const float*)d_in[18];
    const float* prop_b1  = (const float*)d_in[19];
    const float* prop_w2  = (const float*)d_in[20];
    const float* prop_b2  = (const float*)d_in[21];
    const float* rel_w1   = (const float*)d_in[22];
    const float* rel_b1   = (const float*)d_in[23];
    const float* rel_w2   = (const float*)d_in[24];
    const float* rel_b2   = (const float*)d_in[25];
    const float* dyn_w1   = (const float*)d_in[26];
    const float* dyn_b1   = (const float*)d_in[27];
    const float* dyn_w2   = (const float*)d_in[28];
    const float* dyn_b2   = (const float*)d_in[29];
    const float* dyn_w3   = (const float*)d_in[30];
    const float* dyn_b3   = (const float*)d_in[31];
    const float* gravity  = (const float*)d_in[32];
    const float* rend_w1  = (const float*)d_in[33];
    const float* rend_b1  = (const float*)d_in[34];
    const float* rend_w2  = (const float*)d_in[35];
    const float* rend_b2  = (const float*)d_in[36];
    float* out = (float*)d_out;

    float* w      = (float*)d_ws;
    float* stats  = w + OFF_STATS;
    float* kv     = w + OFF_KV;
    float* slots  = w + OFF_SLOTS;
    float* qg     = w + OFF_Q;
    float* apart  = w + OFF_APART;
    float* objs   = w + OFF_OBJ;
    float* feat   = w + OFF_FEAT;             /* [next_objects(4096) | relations(65536)] */
    float* relout = feat + 4096;
    float* p1     = w + OFF_P1;
    float* hrend  = w + OFF_HREND;
    float* p3     = w + OFF_P3;
    float* p2     = w + OFF_P2;

    k_stats<<<4096, 256, 0, stream>>>(obs, stats);
    k_kv<<<dim3(128, 2), 256, 0, stream>>>(obs, stats, ln_in_g, ln_in_b, Wk, Wv, kv);
    k_slots_init<<<16, 256, 0, stream>>>(mu, lsig, noise, slots);
    k_q<<<32, 128, 0, stream>>>(slots, Wq, ln_s_g, ln_s_b, qg);

    for (int it = 0; it < 3; ++it) {
        k_attn<<<256, 256, 0, stream>>>(kv, qg, apart);
        k_umq<<<32, 256, 0, stream>>>(apart, slots, ln_m_g, ln_m_b,
                                      mlp_w1, mlp_b1, mlp_w2, mlp_b2,
                                      ln_s_g, ln_s_b, Wq, qg, (it < 2) ? 1 : 0);
    }

    k_propdyn<<<32, 256, 0, stream>>>(slots, prop_w1, prop_b1, prop_w2, prop_b2,
                                      action, dyn_w1, dyn_b1, dyn_w2, dyn_b2,
                                      dyn_w3, dyn_b3, gravity, objs, feat);
    k_rel<<<1024, 128, 0, stream>>>(objs, rel_w1, rel_b1, rel_w2, rel_b2, relout);

    k_rend1<<<1024, 384, 0, stream>>>(feat, rend_w1, p1);
    k_rend2a<<<dim3(6, 16), 256, 0, stream>>>(p1, p2);
    k_rend2b<<<6, 256, 0, stream>>>(p2, rend_b1, hrend);
    k_rend3<<<48, 256, 0, stream>>>(hrend, rend_w2, p3);
    k_rend4<<<3, 256, 0, stream>>>(p3, rend_b2, out);
}

// Round 2
// 1000.694 us; speedup vs baseline: 2.3571x; 2.3571x over previous
//
#include <hip/hip_runtime.h>
#include <hip/hip_bf16.h>
#include <math.h>

#define NPIX    16384
#define OBSD    768
#define OBJ     128
#define NS      32
#define HIDD    256
#define RELD    64
#define ACTD    16
#define QSCALE  0.08838834764831845f   /* 128^-0.5 */
#define LNEPS   1e-5f
#define ATEPS   1e-8f
#define DTC     0.1f

/* ---- workspace layout (floats) ---- */
#define OFF_STATS 0                         /* 16384*2          */
#define OFF_KV    (OFF_STATS + NPIX*2)      /* 16384*256        */
#define OFF_SLOTS (OFF_KV + NPIX*256)       /* 4096             */
#define OFF_Q     (OFF_SLOTS + 4096)        /* 4096             */
#define OFF_H     (OFF_Q + 4096)            /* 4096 (unused)    */
#define OFF_APART (OFF_H + 4096)            /* 256*4128         */
#define OFF_OBJ   (OFF_APART + 256*4128)    /* 4096             */
#define OFF_FEAT  (OFF_OBJ + 4096)          /* 4096 + 65536     */
#define OFF_P1    (OFF_FEAT + 69632)        /* 1024*1536        */
#define OFF_HREND (OFF_P1 + 1024*1536)      /* 1536 (unused)    */
#define OFF_P3    (OFF_HREND + 1536)        /* 48*768           */
#define OFF_P2    (OFF_P3 + 48*768)         /* 16*1536          */

/* ================= LN stats: mean/rstd per pixel row ================= */
__global__ __launch_bounds__(256) void k_stats(const float* __restrict__ obs,
                                               float* __restrict__ stats)
{
    int lane = threadIdx.x & 63;
    int w    = threadIdx.x >> 6;
    int row  = blockIdx.x * 4 + w;
    const float* o = obs + (size_t)row * OBSD;
    float s = 0.f, s2 = 0.f;
    #pragma unroll
    for (int i = 0; i < 12; ++i) { float v = o[lane + 64*i]; s += v; s2 += v*v; }
    #pragma unroll
    for (int off = 32; off > 0; off >>= 1) {
        s  += __shfl_down(s,  off);
        s2 += __shfl_down(s2, off);
    }
    if (lane == 0) {
        float m   = s  * (1.f/OBSD);
        float var = s2 * (1.f/OBSD) - m*m;
        stats[row*2]   = m;
        stats[row*2+1] = rsqrtf(var + LNEPS);
    }
}

/* ====== kv GEMM: x_ln(16384x768) @ [Wk|Wv](768x256) -> kv[n][256] ======
   (round-0 proven version: single LDS buffer, two barriers per K-step) */
#define STA 129
__global__ __launch_bounds__(256) void k_kv(
    const float* __restrict__ obs, const float* __restrict__ stats,
    const float* __restrict__ g, const float* __restrict__ b,
    const float* __restrict__ Wk, const float* __restrict__ Wv,
    float* __restrict__ kv)
{
    __shared__ float As[32*STA];   /* [kk][m], padded */
    __shared__ float Bs[32*128];   /* [kk][jj]        */
    __shared__ float sm[128], sr[128];
    int t  = threadIdx.x;
    int m0 = blockIdx.x * 128;
    int nsel = blockIdx.y;
    const float* W = nsel ? Wv : Wk;
    int tx = t & 15, ty = t >> 4;
    float acc[8][8];
    #pragma unroll
    for (int i = 0; i < 8; ++i) {
        #pragma unroll
        for (int j = 0; j < 8; ++j) acc[i][j] = 0.f;
    }
    if (t < 128) { sm[t] = stats[(m0+t)*2]; sr[t] = stats[(m0+t)*2+1]; }

    for (int ks = 0; ks < 24; ++ks) {
        int k0 = ks * 32;
        __syncthreads();
        #pragma unroll
        for (int r = 0; r < 16; ++r) {          /* A: 128m x 32kk */
            int id = t + 256*r;
            int m  = id >> 5, kk = id & 31;
            float val = obs[(size_t)(m0+m)*OBSD + k0 + kk];
            val = (val - sm[m]) * sr[m] * g[k0+kk] + b[k0+kk];
            As[kk*STA + m] = val;
        }
        #pragma unroll
        for (int r = 0; r < 16; ++r) {          /* B: 32kk x 128jj */
            int id = t + 256*r;
            int kk = id >> 7, jj = id & 127;
            Bs[kk*128 + jj] = W[(size_t)(k0+kk)*128 + jj];
        }
        __syncthreads();
        #pragma unroll
        for (int kk = 0; kk < 32; ++kk) {
            float a8[8], b8[8];
            #pragma unroll
            for (int i = 0; i < 8; ++i) a8[i] = As[kk*STA + ty*8 + i];
            float4 u0 = *(const float4*)&Bs[kk*128 + tx*8];
            float4 u1 = *(const float4*)&Bs[kk*128 + tx*8 + 4];
            b8[0]=u0.x; b8[1]=u0.y; b8[2]=u0.z; b8[3]=u0.w;
            b8[4]=u1.x; b8[5]=u1.y; b8[6]=u1.z; b8[7]=u1.w;
            #pragma unroll
            for (int i = 0; i < 8; ++i) {
                #pragma unroll
                for (int j = 0; j < 8; ++j)
                    acc[i][j] = fmaf(a8[i], b8[j], acc[i][j]);
            }
        }
    }
    #pragma unroll
    for (int i = 0; i < 8; ++i) {
        size_t row = (size_t)(m0 + ty*8 + i);
        float4 o0 = make_float4(acc[i][0], acc[i][1], acc[i][2], acc[i][3]);
        float4 o1 = make_float4(acc[i][4], acc[i][5], acc[i][6], acc[i][7]);
        *(float4*)&kv[row*256 + nsel*128 + tx*8]     = o0;
        *(float4*)&kv[row*256 + nsel*128 + tx*8 + 4] = o1;
    }
}

/* ====== fused: slot init + q = LN(slots) @ Wq ====== */
__global__ __launch_bounds__(128) void k_initq(
    const float* __restrict__ mu, const float* __restrict__ lsig,
    const float* __restrict__ noise, float* __restrict__ slots,
    const float* __restrict__ Wq,
    const float* __restrict__ g, const float* __restrict__ b,
    float* __restrict__ qg)
{
    int s = blockIdx.x, t = threadIdx.x;
    float x = mu[t] + expf(lsig[t]) * noise[s*128 + t];
    slots[s*128 + t] = x;
    __shared__ float red[128];
    __shared__ float hh[128];
    red[t] = x; __syncthreads();
    for (int off = 64; off > 0; off >>= 1) { if (t < off) red[t] += red[t+off]; __syncthreads(); }
    float mean = red[0] * (1.f/128.f); __syncthreads();
    float dx = x - mean;
    red[t] = dx*dx; __syncthreads();
    for (int off = 64; off > 0; off >>= 1) { if (t < off) red[t] += red[t+off]; __syncthreads(); }
    float var = red[0] * (1.f/128.f);
    hh[t] = dx * rsqrtf(var + LNEPS) * g[t] + b[t];
    __syncthreads();
    float acc = 0.f;
    for (int d = 0; d < 128; ++d) acc = fmaf(hh[d], Wq[d*128 + t], acc);
    qg[s*128 + t] = acc;
}

/* ====== attention tile: 64 pixels/block; softmax over slots; partial U,Ssum ====== */
#define STK 129
#define STQ 132
#define STT 36
__global__ __launch_bounds__(256) void k_attn(
    const float* __restrict__ kv, const float* __restrict__ qg,
    float* __restrict__ part)
{
    __shared__ float q_lds[NS*STQ];
    __shared__ float k_lds[64*STK];
    __shared__ float at[64*STT];
    int t   = threadIdx.x;
    int px0 = blockIdx.x * 64;
    #pragma unroll
    for (int r = 0; r < 16; ++r) {
        int id = t + 256*r;
        int s = id >> 7, d = id & 127;
        q_lds[s*STQ + d] = qg[id];
    }
    #pragma unroll
    for (int r = 0; r < 32; ++r) {
        int id = t + 256*r;
        int p = id >> 7, d = id & 127;
        k_lds[p*STK + d] = kv[(size_t)(px0+p)*256 + d];
    }
    __syncthreads();

    /* logits: wave w handles slot set {4u+w}, lane = pixel */
    int wv = t >> 6, p = t & 63;
    float acc[8];
    #pragma unroll
    for (int u = 0; u < 8; ++u) acc[u] = 0.f;
    for (int dc = 0; dc < 4; ++dc) {
        float kr[32];
        #pragma unroll
        for (int d = 0; d < 32; ++d) kr[d] = k_lds[p*STK + dc*32 + d];
        #pragma unroll
        for (int u = 0; u < 8; ++u) {
            int s = u*4 + wv;
            const float* qp = &q_lds[s*STQ + dc*32];
            #pragma unroll
            for (int ii = 0; ii < 8; ++ii) {
                float4 q4 = *(const float4*)(qp + 4*ii);
                acc[u] = fmaf(q4.x, kr[4*ii+0], acc[u]);
                acc[u] = fmaf(q4.y, kr[4*ii+1], acc[u]);
                acc[u] = fmaf(q4.z, kr[4*ii+2], acc[u]);
                acc[u] = fmaf(q4.w, kr[4*ii+3], acc[u]);
            }
        }
    }
    #pragma unroll
    for (int u = 0; u < 8; ++u) at[p*STT + u*4 + wv] = acc[u] * QSCALE;
    __syncthreads();

    /* softmax over slots, per pixel */
    if (t < 64) {
        float mx = -1e30f;
        #pragma unroll
        for (int s = 0; s < NS; ++s) mx = fmaxf(mx, at[t*STT + s]);
        float smv = 0.f;
        #pragma unroll
        for (int s = 0; s < NS; ++s) { float e = expf(at[t*STT + s] - mx); at[t*STT + s] = e; smv += e; }
        float inv = 1.f / smv;
        #pragma unroll
        for (int s = 0; s < NS; ++s) at[t*STT + s] *= inv;
    }
    __syncthreads();

    /* U[s][d] partial + Ssum[s] partial */
    int d = t & 127, sh = t >> 7;
    float u16[16];
    #pragma unroll
    for (int i = 0; i < 16; ++i) u16[i] = 0.f;
    const float* vbase = kv + (size_t)px0*256 + 128 + d;
    #pragma unroll 4
    for (int pp = 0; pp < 64; ++pp) {
        float vv = vbase[(size_t)pp*256];
        const float4* ap = (const float4*)&at[pp*STT + sh*16];
        #pragma unroll
        for (int gg = 0; gg < 4; ++gg) {
            float4 a4 = ap[gg];
            u16[4*gg+0] = fmaf(a4.x, vv, u16[4*gg+0]);
            u16[4*gg+1] = fmaf(a4.y, vv, u16[4*gg+1]);
            u16[4*gg+2] = fmaf(a4.z, vv, u16[4*gg+2]);
            u16[4*gg+3] = fmaf(a4.w, vv, u16[4*gg+3]);
        }
    }
    float* P = part + (size_t)blockIdx.x * 4128;
    #pragma unroll
    for (int g2 = 0; g2 < 16; ++g2) P[(sh*16 + g2)*128 + d] = u16[g2];
    if (t < 32) {
        float ss = 0.f;
        for (int pp = 0; pp < 64; ++pp) ss += at[pp*STT + t];
        P[4096 + t] = ss;
    }
}

/* ====== fused: reduce partials -> slot update -> LN -> MLP residual -> q(next) ====== */
__global__ __launch_bounds__(256) void k_umq(
    const float* __restrict__ part, float* __restrict__ slots,
    const float* __restrict__ gm, const float* __restrict__ bm,
    const float* __restrict__ w1, const float* __restrict__ b1,
    const float* __restrict__ w2, const float* __restrict__ b2,
    const float* __restrict__ gs, const float* __restrict__ bs,
    const float* __restrict__ Wq, float* __restrict__ qg, int do_q)
{
    int s = blockIdx.x, t = threadIdx.x;
    int d = t & 127, half = t >> 7;
    __shared__ float red[256];
    __shared__ float ssred[2];
    __shared__ float xs[128], hm[128], hid[256];

    /* partial reduce: halves split the 256 attn blocks */
    float u = 0.f, ss = 0.f;
    const float* P0 = part + (size_t)(half * 128) * 4128;
    for (int bb = 0; bb < 128; ++bb) {
        const float* P = P0 + (size_t)bb * 4128;
        u  += P[s*128 + d];
        ss += P[4096 + s];
    }
    red[t] = u;
    if (d == 0) ssred[half] = ss;
    __syncthreads();
    if (half == 0)
        xs[d] = slots[s*128 + d] + (red[d] + red[d+128]) / (ssred[0] + ssred[1] + ATEPS);
    __syncthreads();

    /* LN(xs) -> hm */
    red[t] = (half == 0) ? xs[d] : 0.f;
    __syncthreads();
    #pragma unroll
    for (int off = 128; off > 0; off >>= 1) { if (t < off) red[t] += red[t+off]; __syncthreads(); }
    float mean = red[0] * (1.f/128.f);
    __syncthreads();
    { float dx = (half == 0) ? (xs[d] - mean) : 0.f; red[t] = dx*dx; }
    __syncthreads();
    #pragma unroll
    for (int off = 128; off > 0; off >>= 1) { if (t < off) red[t] += red[t+off]; __syncthreads(); }
    float rstd = rsqrtf(red[0] * (1.f/128.f) + LNEPS);
    __syncthreads();
    if (half == 0) hm[d] = (xs[d] - mean) * rstd * gm[d] + bm[d];
    __syncthreads();

    /* mlp: hid = relu(hm@w1+b1); slots = xs + hid@w2+b2 */
    float a = b1[t];
    for (int c = 0; c < 128; ++c) a = fmaf(hm[c], w1[c*256 + t], a);
    hid[t] = fmaxf(a, 0.f);
    __syncthreads();
    if (half == 0) {
        float o = b2[d];
        for (int j = 0; j < 256; ++j) o = fmaf(hid[j], w2[j*128 + d], o);
        float xn = xs[d] + o;
        slots[s*128 + d] = xn;
        xs[d] = xn;
    }
    __syncthreads();

    if (do_q) {
        /* q for next iteration: LN(slots_new) @ Wq */
        red[t] = (half == 0) ? xs[d] : 0.f;
        __syncthreads();
        #pragma unroll
        for (int off = 128; off > 0; off >>= 1) { if (t < off) red[t] += red[t+off]; __syncthreads(); }
        float m2 = red[0] * (1.f/128.f);
        __syncthreads();
        { float dx = (half == 0) ? (xs[d] - m2) : 0.f; red[t] = dx*dx; }
        __syncthreads();
        #pragma unroll
        for (int off = 128; off > 0; off >>= 1) { if (t < off) red[t] += red[t+off]; __syncthreads(); }
        float r2 = rsqrtf(red[0] * (1.f/128.f) + LNEPS);
        __syncthreads();
        if (half == 0) hm[d] = (xs[d] - m2) * r2 * gs[d] + bs[d];
        __syncthreads();
        float acc = 0.f;
        for (int c = half*64; c < half*64 + 64; ++c) acc = fmaf(hm[c], Wq[c*128 + d], acc);
        red[t] = acc;
        __syncthreads();
        if (half == 0) qg[s*128 + d] = red[d] + red[d+128];
    }
}

/* ====== fused: objects = prop MLP; then dynamics -> feat[0:4096] ====== */
__global__ __launch_bounds__(256) void k_propdyn(
    const float* __restrict__ slots,
    const float* __restrict__ pw1, const float* __restrict__ pb1,
    const float* __restrict__ pw2, const float* __restrict__ pb2,
    const float* __restrict__ action,
    const float* __restrict__ dw1, const float* __restrict__ db1,
    const float* __restrict__ dw2, const float* __restrict__ db2,
    const float* __restrict__ dw3, const float* __restrict__ db3,
    const float* __restrict__ gravity,
    float* __restrict__ objects, float* __restrict__ feat)
{
    int s = blockIdx.x, t = threadIdx.x;
    __shared__ float h[128], hid[256], inp[144], h2[256];
    if (t < 128) h[t] = slots[s*128 + t];
    __syncthreads();
    float a = pb1[t];
    for (int c = 0; c < 128; ++c) a = fmaf(h[c], pw1[c*256 + t], a);
    hid[t] = fmaxf(a, 0.f);
    __syncthreads();
    if (t < 128) {
        float o = pb2[t];
        for (int j = 0; j < 256; ++j) o = fmaf(hid[j], pw2[j*128 + t], o);
        objects[s*128 + t] = o;
        inp[t] = o;
    } else if (t < 144) {
        inp[t] = action[t - 128];
    }
    __syncthreads();
    float a1 = db1[t];
    for (int c = 0; c < 144; ++c) a1 = fmaf(inp[c], dw1[c*256 + t], a1);
    hid[t] = fmaxf(a1, 0.f);
    __syncthreads();
    float a2 = db2[t];
    for (int c = 0; c < 256; ++c) a2 = fmaf(hid[c], dw2[c*256 + t], a2);
    h2[t] = fmaxf(a2, 0.f);
    __syncthreads();
    if (t < 128) {
        float dlt = db3[t];
        for (int c = 0; c < 256; ++c) dlt = fmaf(h2[c], dw3[c*128 + t], dlt);
        if (t < 3) dlt += gravity[t] * DTC;
        feat[s*128 + t] = inp[t] + dlt * DTC;
    }
}

/* ====== relations: per (i,j) pair MLP 256->128(relu)->64 ====== */
__global__ __launch_bounds__(128) void k_rel(
    const float* __restrict__ objects, const float* __restrict__ w1, const float* __restrict__ b1,
    const float* __restrict__ w2, const float* __restrict__ b2, float* __restrict__ rel_out)
{
    int pr = blockIdx.x; int i = pr >> 5, j = pr & 31; int t = threadIdx.x;
    __shared__ float pair[256], hid[128];
    pair[t]       = objects[i*128 + t];
    pair[128 + t] = objects[j*128 + t];
    __syncthreads();
    float a = b1[t];
    for (int c = 0; c < 256; ++c) a = fmaf(pair[c], w1[c*128 + t], a);
    hid[t] = fmaxf(a, 0.f);
    __syncthreads();
    if (t < 64) {
        float o = b2[t];
        for (int c = 0; c < 128; ++c) o = fmaf(hid[c], w2[c*64 + t], o);
        rel_out[(size_t)pr*64 + t] = o;
    }
}

/* ====== renderer stage 1: feat @ rend_w1 partials (the 428 MB read) ====== */
__global__ __launch_bounds__(384) void k_rend1(
    const float* __restrict__ feat, const float* __restrict__ w1, float* __restrict__ p1)
{
    int b = blockIdx.x, t = threadIdx.x;
    float4 acc = make_float4(0.f, 0.f, 0.f, 0.f);
    int i0 = b * 68;
    #pragma unroll 4
    for (int r = 0; r < 68; ++r) {
        int i = i0 + r;
        float f = feat[i];
        float4 w = *(const float4*)(w1 + (size_t)i * 1536 + 4*t);
        acc.x = fmaf(f, w.x, acc.x);
        acc.y = fmaf(f, w.y, acc.y);
        acc.z = fmaf(f, w.z, acc.z);
        acc.w = fmaf(f, w.w, acc.w);
    }
    *(float4*)(p1 + (size_t)b * 1536 + 4*t) = acc;
}

/* ====== renderer stage 2a: tree-reduce partials (6x16 blocks) ====== */
__global__ __launch_bounds__(256) void k_rend2a(
    const float* __restrict__ p1, float* __restrict__ p2)
{
    int j  = blockIdx.x * 256 + threadIdx.x;
    int sl = blockIdx.y;
    const float* P = p1 + (size_t)sl * 64 * 1536;
    float a0 = 0.f, a1 = 0.f, a2 = 0.f, a3 = 0.f;
    #pragma unroll 4
    for (int bb = 0; bb < 64; bb += 4) {
        a0 += P[(size_t)(bb+0)*1536 + j];
        a1 += P[(size_t)(bb+1)*1536 + j];
        a2 += P[(size_t)(bb+2)*1536 + j];
        a3 += P[(size_t)(bb+3)*1536 + j];
    }
    p2[sl*1536 + j] = (a0+a1) + (a2+a3);
}

/* ====== fused renderer 2b+3: finish h then h@rend_w2 partials ====== */
__global__ __launch_bounds__(256) void k_rend23(
    const float* __restrict__ p2, const float* __restrict__ b1,
    const float* __restrict__ w2, float* __restrict__ p3)
{
    int bj = blockIdx.x, t = threadIdx.x;
    int j0 = bj * 32;
    __shared__ float hh[32];
    if (t < 32) {
        float a = b1[j0 + t];
        #pragma unroll
        for (int sl = 0; sl < 16; ++sl) a += p2[sl*1536 + j0 + t];
        hh[t] = fmaxf(a, 0.f);
    }
    __syncthreads();
    float a0 = 0.f, a1 = 0.f, a2 = 0.f;
    #pragma unroll
    for (int j = 0; j < 32; ++j) {
        float hj = hh[j];
        const float* w = w2 + (size_t)(j0 + j) * 768;
        a0 = fmaf(hj, w[t],       a0);
        a1 = fmaf(hj, w[t + 256], a1);
        a2 = fmaf(hj, w[t + 512], a2);
    }
    p3[(size_t)bj*768 + t]       = a0;
    p3[(size_t)bj*768 + t + 256] = a1;
    p3[(size_t)bj*768 + t + 512] = a2;
}

/* ====== renderer stage 4: reduce + bias -> out(768) ====== */
__global__ __launch_bounds__(256) void k_rend4(
    const float* __restrict__ p3, const float* __restrict__ b2, float* __restrict__ out)
{
    int m = blockIdx.x * 256 + threadIdx.x;
    float a = b2[m];
    #pragma unroll
    for (int bj = 0; bj < 48; ++bj) a += p3[(size_t)bj*768 + m];
    out[m] = a;
}

extern "C" void kernel_launch(void* const* d_in, const int* in_sizes, int n_in,
                              void* d_out, int out_size, void* d_ws, size_t ws_size,
                              hipStream_t stream) {
    (void)in_sizes; (void)n_in; (void)out_size; (void)ws_size;
    const float* obs      = (const float*)d_in[0];
    const float* action   = (const float*)d_in[1];
    const float* noise    = (const float*)d_in[2];
    const float* mu       = (const float*)d_in[3];
    const float* lsig     = (const float*)d_in[4];
    const float* ln_in_g  = (const float*)d_in[5];
    const float* ln_in_b  = (const float*)d_in[6];
    const float* ln_s_g   = (const float*)d_in[7];
    const float* ln_s_b   = (const float*)d_in[8];
    const float* ln_m_g   = (const float*)d_in[9];
    const float* ln_m_b   = (const float*)d_in[10];
    const float* Wq       = (const float*)d_in[11];
    const float* Wk       = (const float*)d_in[12];
    const float* Wv       = (const float*)d_in[13];
    const float* mlp_w1   = (const float*)d_in[14];
    const float* mlp_b1   = (const float*)d_in[15];
    const float* mlp_w2   = (const float*)d_in[16];
    const float* mlp_b2   = (const float*)d_in[17];
    const float* prop_w1  = (const float*)d_in[18];
    const float* prop_b1  = (const float*)d_in[19];
    const float* prop_w2  = (const float*)d_in[20];
    const float* prop_b2  = (const float*)d_in[21];
    const float* rel_w1   = (const float*)d_in[22];
    const float* rel_b1   = (const float*)d_in[23];
    const float* rel_w2   = (const float*)d_in[24];
    const float* rel_b2   = (const float*)d_in[25];
    const float* dyn_w1   = (const float*)d_in[26];
    const float* dyn_b1   = (const float*)d_in[27];
    const float* dyn_w2   = (const float*)d_in[28];
    const float* dyn_b2   = (const float*)d_in[29];
    const float* dyn_w3   = (const float*)d_in[30];
    const float* dyn_b3   = (const float*)d_in[31];
    const float* gravity  = (const float*)d_in[32];
    const float* rend_w1  = (const float*)d_in[33];
    const float* rend_b1  = (const float*)d_in[34];
    const float* rend_w2  = (const float*)d_in[35];
    const float* rend_b2  = (const float*)d_in[36];
    float* out = (float*)d_out;

    float* w      = (float*)d_ws;
    float* stats  = w + OFF_STATS;
    float* kv     = w + OFF_KV;
    float* slots  = w + OFF_SLOTS;
    float* qg     = w + OFF_Q;
    float* apart  = w + OFF_APART;
    float* objs   = w + OFF_OBJ;
    float* feat   = w + OFF_FEAT;             /* [next_objects(4096) | relations(65536)] */
    float* relout = feat + 4096;
    float* p1     = w + OFF_P1;
    float* p3     = w + OFF_P3;
    float* p2     = w + OFF_P2;

    k_stats<<<4096, 256, 0, stream>>>(obs, stats);
    k_kv<<<dim3(128, 2), 256, 0, stream>>>(obs, stats, ln_in_g, ln_in_b, Wk, Wv, kv);
    k_initq<<<32, 128, 0, stream>>>(mu, lsig, noise, slots, Wq, ln_s_g, ln_s_b, qg);

    for (int it = 0; it < 3; ++it) {
        k_attn<<<256, 256, 0, stream>>>(kv, qg, apart);
        k_umq<<<32, 256, 0, stream>>>(apart, slots, ln_m_g, ln_m_b,
                                      mlp_w1, mlp_b1, mlp_w2, mlp_b2,
                                      ln_s_g, ln_s_b, Wq, qg, (it < 2) ? 1 : 0);
    }

    k_propdyn<<<32, 256, 0, stream>>>(slots, prop_w1, prop_b1, prop_w2, prop_b2,
                                      action, dyn_w1, dyn_b1, dyn_w2, dyn_b2,
                                      dyn_w3, dyn_b3, gravity, objs, feat);
    k_rel<<<1024, 128, 0, stream>>>(objs, rel_w1, rel_b1, rel_w2, rel_b2, relout);

    k_rend1<<<1024, 384, 0, stream>>>(feat, rend_w1, p1);
    k_rend2a<<<dim3(6, 16), 256, 0, stream>>>(p1, p2);
    k_rend23<<<48, 256, 0, stream>>>(p2, rend_b1, rend_w2, p3);
    k_rend4<<<3, 256, 0, stream>>>(p3, rend_b2, out);
}

// Round 4
// 983.513 us; speedup vs baseline: 2.3982x; 1.0175x over previous
//
#include <hip/hip_runtime.h>
#include <hip/hip_bf16.h>
#include <math.h>

#define NPIX    16384
#define OBSD    768
#define OBJ     128
#define NS      32
#define HIDD    256
#define RELD    64
#define ACTD    16
#define QSCALE  0.08838834764831845f   /* 128^-0.5 */
#define LNEPS   1e-5f
#define ATEPS   1e-8f
#define DTC     0.1f

/* ---- workspace layout (floats) ---- */
#define OFF_STATS 0                         /* 16384*2          */
#define OFF_KV    (OFF_STATS + NPIX*2)      /* 16384*256        */
#define OFF_SLOTS (OFF_KV + NPIX*256)       /* 4096             */
#define OFF_Q     (OFF_SLOTS + 4096)        /* 4096             */
#define OFF_H     (OFF_Q + 4096)            /* 4096 (unused)    */
#define OFF_APART (OFF_H + 4096)            /* 256*4128         */
#define OFF_OBJ   (OFF_APART + 256*4128)    /* 4096             */
#define OFF_FEAT  (OFF_OBJ + 4096)          /* 4096 + 65536     */
#define OFF_P1    (OFF_FEAT + 69632)        /* 1024*1536        */
#define OFF_HREND (OFF_P1 + 1024*1536)      /* 1536 (unused)    */
#define OFF_P3    (OFF_HREND + 1536)        /* 48*768           */

/* ====== fused: LN stats (blocks 0..4095) + slot-init+q (blocks 4096..4127) ====== */
__global__ __launch_bounds__(256) void k_stats_initq(
    const float* __restrict__ obs, float* __restrict__ stats,
    const float* __restrict__ mu, const float* __restrict__ lsig,
    const float* __restrict__ noise, float* __restrict__ slots,
    const float* __restrict__ Wq,
    const float* __restrict__ g, const float* __restrict__ b,
    float* __restrict__ qg)
{
    __shared__ float red[256];
    __shared__ float hh[128];
    int t = threadIdx.x;
    if (blockIdx.x < 4096) {
        int lane = t & 63;
        int w    = t >> 6;
        int row  = blockIdx.x * 4 + w;
        const float* o = obs + (size_t)row * OBSD;
        float s = 0.f, s2 = 0.f;
        #pragma unroll
        for (int i = 0; i < 12; ++i) { float v = o[lane + 64*i]; s += v; s2 += v*v; }
        #pragma unroll
        for (int off = 32; off > 0; off >>= 1) {
            s  += __shfl_down(s,  off);
            s2 += __shfl_down(s2, off);
        }
        if (lane == 0) {
            float m   = s  * (1.f/OBSD);
            float var = s2 * (1.f/OBSD) - m*m;
            stats[row*2]   = m;
            stats[row*2+1] = rsqrtf(var + LNEPS);
        }
        return;
    }
    /* ---- initq: slot init + q = LN(slots)@Wq ---- */
    int s = blockIdx.x - 4096;
    int d = t & 127, half = t >> 7;
    float x = 0.f;
    if (t < 128) {
        x = mu[t] + expf(lsig[t]) * noise[s*128 + t];
        slots[s*128 + t] = x;
    }
    red[t] = (t < 128) ? x : 0.f;
    __syncthreads();
    #pragma unroll
    for (int off = 128; off > 0; off >>= 1) { if (t < off) red[t] += red[t+off]; __syncthreads(); }
    float mean = red[0] * (1.f/128.f);
    __syncthreads();
    { float dx = (t < 128) ? (x - mean) : 0.f; red[t] = dx*dx; }
    __syncthreads();
    #pragma unroll
    for (int off = 128; off > 0; off >>= 1) { if (t < off) red[t] += red[t+off]; __syncthreads(); }
    float rstd = rsqrtf(red[0] * (1.f/128.f) + LNEPS);
    __syncthreads();
    if (t < 128) hh[t] = (x - mean) * rstd * g[t] + b[t];
    __syncthreads();
    float acc = 0.f;
    for (int c = half*64; c < half*64 + 64; ++c) acc = fmaf(hh[c], Wq[c*128 + d], acc);
    red[t] = acc;
    __syncthreads();
    if (t < 128) qg[s*128 + t] = red[t] + red[t+128];
}

/* ====== kv GEMM: x_ln(16384x768) @ [Wk|Wv](768x256) -> kv[n][256] ======
   (proven version: single LDS buffer, two barriers per K-step) */
#define STA 129
__global__ __launch_bounds__(256) void k_kv(
    const float* __restrict__ obs, const float* __restrict__ stats,
    const float* __restrict__ g, const float* __restrict__ b,
    const float* __restrict__ Wk, const float* __restrict__ Wv,
    float* __restrict__ kv)
{
    __shared__ float As[32*STA];   /* [kk][m], padded */
    __shared__ float Bs[32*128];   /* [kk][jj]        */
    __shared__ float sm[128], sr[128];
    int t  = threadIdx.x;
    int m0 = blockIdx.x * 128;
    int nsel = blockIdx.y;
    const float* W = nsel ? Wv : Wk;
    int tx = t & 15, ty = t >> 4;
    float acc[8][8];
    #pragma unroll
    for (int i = 0; i < 8; ++i) {
        #pragma unroll
        for (int j = 0; j < 8; ++j) acc[i][j] = 0.f;
    }
    if (t < 128) { sm[t] = stats[(m0+t)*2]; sr[t] = stats[(m0+t)*2+1]; }

    for (int ks = 0; ks < 24; ++ks) {
        int k0 = ks * 32;
        __syncthreads();
        #pragma unroll
        for (int r = 0; r < 16; ++r) {          /* A: 128m x 32kk */
            int id = t + 256*r;
            int m  = id >> 5, kk = id & 31;
            float val = obs[(size_t)(m0+m)*OBSD + k0 + kk];
            val = (val - sm[m]) * sr[m] * g[k0+kk] + b[k0+kk];
            As[kk*STA + m] = val;
        }
        #pragma unroll
        for (int r = 0; r < 16; ++r) {          /* B: 32kk x 128jj */
            int id = t + 256*r;
            int kk = id >> 7, jj = id & 127;
            Bs[kk*128 + jj] = W[(size_t)(k0+kk)*128 + jj];
        }
        __syncthreads();
        #pragma unroll
        for (int kk = 0; kk < 32; ++kk) {
            float a8[8], b8[8];
            #pragma unroll
            for (int i = 0; i < 8; ++i) a8[i] = As[kk*STA + ty*8 + i];
            float4 u0 = *(const float4*)&Bs[kk*128 + tx*8];
            float4 u1 = *(const float4*)&Bs[kk*128 + tx*8 + 4];
            b8[0]=u0.x; b8[1]=u0.y; b8[2]=u0.z; b8[3]=u0.w;
            b8[4]=u1.x; b8[5]=u1.y; b8[6]=u1.z; b8[7]=u1.w;
            #pragma unroll
            for (int i = 0; i < 8; ++i) {
                #pragma unroll
                for (int j = 0; j < 8; ++j)
                    acc[i][j] = fmaf(a8[i], b8[j], acc[i][j]);
            }
        }
    }
    #pragma unroll
    for (int i = 0; i < 8; ++i) {
        size_t row = (size_t)(m0 + ty*8 + i);
        float4 o0 = make_float4(acc[i][0], acc[i][1], acc[i][2], acc[i][3]);
        float4 o1 = make_float4(acc[i][4], acc[i][5], acc[i][6], acc[i][7]);
        *(float4*)&kv[row*256 + nsel*128 + tx*8]     = o0;
        *(float4*)&kv[row*256 + nsel*128 + tx*8 + 4] = o1;
    }
}

/* ====== attention tile: 64 pixels/block; softmax over slots; partial U,Ssum ====== */
#define STK 129
#define STQ 132
#define STT 36
__global__ __launch_bounds__(256) void k_attn(
    const float* __restrict__ kv, const float* __restrict__ qg,
    float* __restrict__ part)
{
    __shared__ float q_lds[NS*STQ];
    __shared__ float k_lds[64*STK];
    __shared__ float at[64*STT];
    int t   = threadIdx.x;
    int px0 = blockIdx.x * 64;
    #pragma unroll
    for (int r = 0; r < 16; ++r) {
        int id = t + 256*r;
        int s = id >> 7, d = id & 127;
        q_lds[s*STQ + d] = qg[id];
    }
    #pragma unroll
    for (int r = 0; r < 32; ++r) {
        int id = t + 256*r;
        int p = id >> 7, d = id & 127;
        k_lds[p*STK + d] = kv[(size_t)(px0+p)*256 + d];
    }
    __syncthreads();

    /* logits: wave w handles slot set {4u+w}, lane = pixel */
    int wv = t >> 6, p = t & 63;
    float acc[8];
    #pragma unroll
    for (int u = 0; u < 8; ++u) acc[u] = 0.f;
    for (int dc = 0; dc < 4; ++dc) {
        float kr[32];
        #pragma unroll
        for (int d = 0; d < 32; ++d) kr[d] = k_lds[p*STK + dc*32 + d];
        #pragma unroll
        for (int u = 0; u < 8; ++u) {
            int s = u*4 + wv;
            const float* qp = &q_lds[s*STQ + dc*32];
            #pragma unroll
            for (int ii = 0; ii < 8; ++ii) {
                float4 q4 = *(const float4*)(qp + 4*ii);
                acc[u] = fmaf(q4.x, kr[4*ii+0], acc[u]);
                acc[u] = fmaf(q4.y, kr[4*ii+1], acc[u]);
                acc[u] = fmaf(q4.z, kr[4*ii+2], acc[u]);
                acc[u] = fmaf(q4.w, kr[4*ii+3], acc[u]);
            }
        }
    }
    #pragma unroll
    for (int u = 0; u < 8; ++u) at[p*STT + u*4 + wv] = acc[u] * QSCALE;
    __syncthreads();

    /* softmax over slots, per pixel */
    if (t < 64) {
        float mx = -1e30f;
        #pragma unroll
        for (int s = 0; s < NS; ++s) mx = fmaxf(mx, at[t*STT + s]);
        float smv = 0.f;
        #pragma unroll
        for (int s = 0; s < NS; ++s) { float e = expf(at[t*STT + s] - mx); at[t*STT + s] = e; smv += e; }
        float inv = 1.f / smv;
        #pragma unroll
        for (int s = 0; s < NS; ++s) at[t*STT + s] *= inv;
    }
    __syncthreads();

    /* U[s][d] partial + Ssum[s] partial */
    int d = t & 127, sh = t >> 7;
    float u16[16];
    #pragma unroll
    for (int i = 0; i < 16; ++i) u16[i] = 0.f;
    const float* vbase = kv + (size_t)px0*256 + 128 + d;
    #pragma unroll 4
    for (int pp = 0; pp < 64; ++pp) {
        float vv = vbase[(size_t)pp*256];
        const float4* ap = (const float4*)&at[pp*STT + sh*16];
        #pragma unroll
        for (int gg = 0; gg < 4; ++gg) {
            float4 a4 = ap[gg];
            u16[4*gg+0] = fmaf(a4.x, vv, u16[4*gg+0]);
            u16[4*gg+1] = fmaf(a4.y, vv, u16[4*gg+1]);
            u16[4*gg+2] = fmaf(a4.z, vv, u16[4*gg+2]);
            u16[4*gg+3] = fmaf(a4.w, vv, u16[4*gg+3]);
        }
    }
    float* P = part + (size_t)blockIdx.x * 4128;
    #pragma unroll
    for (int g2 = 0; g2 < 16; ++g2) P[(sh*16 + g2)*128 + d] = u16[g2];
    if (t < 32) {
        float ss = 0.f;
        for (int pp = 0; pp < 64; ++pp) ss += at[pp*STT + t];
        P[4096 + t] = ss;
    }
}

/* ====== fused: reduce partials -> slot update -> LN -> MLP residual
         -> q(next iter)  OR  prop MLP + dynamics (last iter) ====== */
__global__ __launch_bounds__(256) void k_umq(
    const float* __restrict__ part, float* __restrict__ slots,
    const float* __restrict__ gm, const float* __restrict__ bm,
    const float* __restrict__ w1, const float* __restrict__ b1,
    const float* __restrict__ w2, const float* __restrict__ b2,
    const float* __restrict__ gs, const float* __restrict__ bs,
    const float* __restrict__ Wq, float* __restrict__ qg,
    const float* __restrict__ pw1, const float* __restrict__ pb1,
    const float* __restrict__ pw2, const float* __restrict__ pb2,
    const float* __restrict__ action,
    const float* __restrict__ dw1, const float* __restrict__ db1,
    const float* __restrict__ dw2, const float* __restrict__ db2,
    const float* __restrict__ dw3, const float* __restrict__ db3,
    const float* __restrict__ gravity,
    float* __restrict__ objects, float* __restrict__ feat, int last)
{
    int s = blockIdx.x, t = threadIdx.x;
    int d = t & 127, half = t >> 7;
    __shared__ float red[256];
    __shared__ float ssred[2];
    __shared__ float xs[128], hm[128], hid[256];
    __shared__ float inp[144], h2[256];

    /* partial reduce: halves split the 256 attn blocks */
    float u = 0.f, ss = 0.f;
    const float* P0 = part + (size_t)(half * 128) * 4128;
    for (int bb = 0; bb < 128; ++bb) {
        const float* P = P0 + (size_t)bb * 4128;
        u  += P[s*128 + d];
        ss += P[4096 + s];
    }
    red[t] = u;
    if (d == 0) ssred[half] = ss;
    __syncthreads();
    if (half == 0)
        xs[d] = slots[s*128 + d] + (red[d] + red[d+128]) / (ssred[0] + ssred[1] + ATEPS);
    __syncthreads();

    /* LN(xs) -> hm */
    red[t] = (half == 0) ? xs[d] : 0.f;
    __syncthreads();
    #pragma unroll
    for (int off = 128; off > 0; off >>= 1) { if (t < off) red[t] += red[t+off]; __syncthreads(); }
    float mean = red[0] * (1.f/128.f);
    __syncthreads();
    { float dx = (half == 0) ? (xs[d] - mean) : 0.f; red[t] = dx*dx; }
    __syncthreads();
    #pragma unroll
    for (int off = 128; off > 0; off >>= 1) { if (t < off) red[t] += red[t+off]; __syncthreads(); }
    float rstd = rsqrtf(red[0] * (1.f/128.f) + LNEPS);
    __syncthreads();
    if (half == 0) hm[d] = (xs[d] - mean) * rstd * gm[d] + bm[d];
    __syncthreads();

    /* mlp: hid = relu(hm@w1+b1); slots = xs + hid@w2+b2 */
    float a = b1[t];
    for (int c = 0; c < 128; ++c) a = fmaf(hm[c], w1[c*256 + t], a);
    hid[t] = fmaxf(a, 0.f);
    __syncthreads();
    if (half == 0) {
        float o = b2[d];
        for (int j = 0; j < 256; ++j) o = fmaf(hid[j], w2[j*128 + d], o);
        float xn = xs[d] + o;
        slots[s*128 + d] = xn;
        xs[d] = xn;
    }
    __syncthreads();

    if (!last) {
        /* q for next iteration: LN(slots_new) @ Wq */
        red[t] = (half == 0) ? xs[d] : 0.f;
        __syncthreads();
        #pragma unroll
        for (int off = 128; off > 0; off >>= 1) { if (t < off) red[t] += red[t+off]; __syncthreads(); }
        float m2 = red[0] * (1.f/128.f);
        __syncthreads();
        { float dx = (half == 0) ? (xs[d] - m2) : 0.f; red[t] = dx*dx; }
        __syncthreads();
        #pragma unroll
        for (int off = 128; off > 0; off >>= 1) { if (t < off) red[t] += red[t+off]; __syncthreads(); }
        float r2 = rsqrtf(red[0] * (1.f/128.f) + LNEPS);
        __syncthreads();
        if (half == 0) hm[d] = (xs[d] - m2) * r2 * gs[d] + bs[d];
        __syncthreads();
        float acc = 0.f;
        for (int c = half*64; c < half*64 + 64; ++c) acc = fmaf(hm[c], Wq[c*128 + d], acc);
        red[t] = acc;
        __syncthreads();
        if (half == 0) qg[s*128 + d] = red[d] + red[d+128];
    } else {
        /* prop MLP -> objects, then dynamics -> feat[0:4096] */
        float a1 = pb1[t];
        for (int c = 0; c < 128; ++c) a1 = fmaf(xs[c], pw1[c*256 + t], a1);
        hid[t] = fmaxf(a1, 0.f);
        __syncthreads();
        if (t < 128) {
            float o = pb2[t];
            for (int j = 0; j < 256; ++j) o = fmaf(hid[j], pw2[j*128 + t], o);
            objects[s*128 + t] = o;
            inp[t] = o;
        } else if (t < 144) {
            inp[t] = action[t - 128];
        }
        __syncthreads();
        float a2 = db1[t];
        for (int c = 0; c < 144; ++c) a2 = fmaf(inp[c], dw1[c*256 + t], a2);
        hid[t] = fmaxf(a2, 0.f);
        __syncthreads();
        float a3 = db2[t];
        for (int c = 0; c < 256; ++c) a3 = fmaf(hid[c], dw2[c*256 + t], a3);
        h2[t] = fmaxf(a3, 0.f);
        __syncthreads();
        if (t < 128) {
            float dlt = db3[t];
            for (int c = 0; c < 256; ++c) dlt = fmaf(h2[c], dw3[c*128 + t], dlt);
            if (t < 3) dlt += gravity[t] * DTC;
            feat[s*128 + t] = inp[t] + dlt * DTC;
        }
    }
}

/* ====== relations: per (i,j) pair MLP 256->128(relu)->64 ====== */
__global__ __launch_bounds__(128) void k_rel(
    const float* __restrict__ objects, const float* __restrict__ w1, const float* __restrict__ b1,
    const float* __restrict__ w2, const float* __restrict__ b2, float* __restrict__ rel_out)
{
    int pr = blockIdx.x; int i = pr >> 5, j = pr & 31; int t = threadIdx.x;
    __shared__ float pair[256], hid[128];
    pair[t]       = objects[i*128 + t];
    pair[128 + t] = objects[j*128 + t];
    __syncthreads();
    float a = b1[t];
    for (int c = 0; c < 256; ++c) a = fmaf(pair[c], w1[c*128 + t], a);
    hid[t] = fmaxf(a, 0.f);
    __syncthreads();
    if (t < 64) {
        float o = b2[t];
        for (int c = 0; c < 128; ++c) o = fmaf(hid[c], w2[c*64 + t], o);
        rel_out[(size_t)pr*64 + t] = o;
    }
}

/* ====== renderer stage 1: feat @ rend_w1 partials (the 428 MB read) ====== */
__global__ __launch_bounds__(384) void k_rend1(
    const float* __restrict__ feat, const float* __restrict__ w1, float* __restrict__ p1)
{
    int b = blockIdx.x, t = threadIdx.x;
    float4 acc = make_float4(0.f, 0.f, 0.f, 0.f);
    int i0 = b * 68;
    #pragma unroll 4
    for (int r = 0; r < 68; ++r) {
        int i = i0 + r;
        float f = feat[i];
        float4 w = *(const float4*)(w1 + (size_t)i * 1536 + 4*t);
        acc.x = fmaf(f, w.x, acc.x);
        acc.y = fmaf(f, w.y, acc.y);
        acc.z = fmaf(f, w.z, acc.z);
        acc.w = fmaf(f, w.w, acc.w);
    }
    *(float4*)(p1 + (size_t)b * 1536 + 4*t) = acc;
}

/* ====== fused renderer 2+3: reduce p1 cols, bias+relu, then h@rend_w2 partials ====== */
__global__ __launch_bounds__(256) void k_rend23(
    const float* __restrict__ p1, const float* __restrict__ b1,
    const float* __restrict__ w2, float* __restrict__ p3)
{
    int bj = blockIdx.x, t = threadIdx.x;
    int j0 = bj * 32;
    int tj = t & 31, tr = t >> 5;
    __shared__ float red2[256];
    __shared__ float hh[32];
    float part = 0.f;
    const float* P = p1 + (size_t)tr * 1536 + j0 + tj;
    #pragma unroll 8
    for (int r = 0; r < 128; ++r) part += P[(size_t)r * 8 * 1536];
    red2[t] = part;
    __syncthreads();
    if (t < 32) {
        float a = b1[j0 + t];
        #pragma unroll
        for (int g = 0; g < 8; ++g) a += red2[g*32 + t];
        hh[t] = fmaxf(a, 0.f);
    }
    __syncthreads();
    float a0 = 0.f, a1 = 0.f, a2 = 0.f;
    #pragma unroll
    for (int j = 0; j < 32; ++j) {
        float hj = hh[j];
        const float* w = w2 + (size_t)(j0 + j) * 768;
        a0 = fmaf(hj, w[t],       a0);
        a1 = fmaf(hj, w[t + 256], a1);
        a2 = fmaf(hj, w[t + 512], a2);
    }
    p3[(size_t)bj*768 + t]       = a0;
    p3[(size_t)bj*768 + t + 256] = a1;
    p3[(size_t)bj*768 + t + 512] = a2;
}

/* ====== renderer stage 4: reduce + bias -> out(768) ====== */
__global__ __launch_bounds__(256) void k_rend4(
    const float* __restrict__ p3, const float* __restrict__ b2, float* __restrict__ out)
{
    int m = blockIdx.x * 256 + threadIdx.x;
    float a = b2[m];
    #pragma unroll
    for (int bj = 0; bj < 48; ++bj) a += p3[(size_t)bj*768 + m];
    out[m] = a;
}

extern "C" void kernel_launch(void* const* d_in, const int* in_sizes, int n_in,
                              void* d_out, int out_size, void* d_ws, size_t ws_size,
                              hipStream_t stream) {
    (void)in_sizes; (void)n_in; (void)out_size; (void)ws_size;
    const float* obs      = (const float*)d_in[0];
    const float* action   = (const float*)d_in[1];
    const float* noise    = (const float*)d_in[2];
    const float* mu       = (const float*)d_in[3];
    const float* lsig     = (const float*)d_in[4];
    const float* ln_in_g  = (const float*)d_in[5];
    const float* ln_in_b  = (const float*)d_in[6];
    const float* ln_s_g   = (const float*)d_in[7];
    const float* ln_s_b   = (const float*)d_in[8];
    const float* ln_m_g   = (const float*)d_in[9];
    const float* ln_m_b   = (const float*)d_in[10];
    const float* Wq       = (const float*)d_in[11];
    const float* Wk       = (const float*)d_in[12];
    const float* Wv       = (const float*)d_in[13];
    const float* mlp_w1   = (const float*)d_in[14];
    const float* mlp_b1   = (const float*)d_in[15];
    const float* mlp_w2   = (const float*)d_in[16];
    const float* mlp_b2   = (const float*)d_in[17];
    const float* prop_w1  = (const float*)d_in[18];
    const float* prop_b1  = (const float*)d_in[19];
    const float* prop_w2  = (const float*)d_in[20];
    const float* prop_b2  = (const float*)d_in[21];
    const float* rel_w1   = (const float*)d_in[22];
    const float* rel_b1   = (const float*)d_in[23];
    const float* rel_w2   = (const float*)d_in[24];
    const float* rel_b2   = (const float*)d_in[25];
    const float* dyn_w1   = (const float*)d_in[26];
    const float* dyn_b1   = (const float*)d_in[27];
    const float* dyn_w2   = (const float*)d_in[28];
    const float* dyn_b2   = (const float*)d_in[29];
    const float* dyn_w3   = (const float*)d_in[30];
    const float* dyn_b3   = (const float*)d_in[31];
    const float* gravity  = (const float*)d_in[32];
    const float* rend_w1  = (const float*)d_in[33];
    const float* rend_b1  = (const float*)d_in[34];
    const float* rend_w2  = (const float*)d_in[35];
    const float* rend_b2  = (const float*)d_in[36];
    float* out = (float*)d_out;

    float* w      = (float*)d_ws;
    float* stats  = w + OFF_STATS;
    float* kv     = w + OFF_KV;
    float* slots  = w + OFF_SLOTS;
    float* qg     = w + OFF_Q;
    float* apart  = w + OFF_APART;
    float* objs   = w + OFF_OBJ;
    float* feat   = w + OFF_FEAT;             /* [next_objects(4096) | relations(65536)] */
    float* relout = feat + 4096;
    float* p1     = w + OFF_P1;
    float* p3     = w + OFF_P3;

    k_stats_initq<<<4128, 256, 0, stream>>>(obs, stats, mu, lsig, noise, slots,
                                            Wq, ln_s_g, ln_s_b, qg);
    k_kv<<<dim3(128, 2), 256, 0, stream>>>(obs, stats, ln_in_g, ln_in_b, Wk, Wv, kv);

    for (int it = 0; it < 3; ++it) {
        k_attn<<<256, 256, 0, stream>>>(kv, qg, apart);
        k_umq<<<32, 256, 0, stream>>>(apart, slots, ln_m_g, ln_m_b,
                                      mlp_w1, mlp_b1, mlp_w2, mlp_b2,
                                      ln_s_g, ln_s_b, Wq, qg,
                                      prop_w1, prop_b1, prop_w2, prop_b2,
                                      action, dyn_w1, dyn_b1, dyn_w2, dyn_b2,
                                      dyn_w3, dyn_b3, gravity,
                                      objs, feat, (it == 2) ? 1 : 0);
    }

    k_rel<<<1024, 128, 0, stream>>>(objs, rel_w1, rel_b1, rel_w2, rel_b2, relout);

    k_rend1<<<1024, 384, 0, stream>>>(feat, rend_w1, p1);
    k_rend23<<<48, 256, 0, stream>>>(p1, rend_b1, rend_w2, p3);
    k_rend4<<<3, 256, 0, stream>>>(p3, rend_b2, out);
}